// Round 1
// baseline (81.600 us; speedup 1.0000x reference)
//
#include <hip/hip_runtime.h>
#include <hip/hip_bf16.h>

// Chamfer distance: B=4, N=M=8192, fp32 points (B,N,3).
// out = 0.5*(mean(sqrt(min_m d(x_n,y_m))) + mean(sqrt(min_n d(x_n,y_m))))
//     = (sum of all 65536 sqrt'd row-mins) / 65536   (since counts are equal)

constexpr int TPB   = 256;   // threads per block
constexpr int XPT   = 4;     // x-points per thread -> 1024 rows per block
constexpr int CHUNK = 1024;  // y-points staged in LDS per block (12 KB)
constexpr int YSPLIT = 8;    // y-dimension split for occupancy
constexpr int NPTS  = 8192;
constexpr int BATCH = 4;

__global__ __launch_bounds__(TPB)
void chamfer_partial(const float* __restrict__ P1, const float* __restrict__ P2,
                     unsigned* __restrict__ minsq) {
    const int b    = blockIdx.y;
    const int dir  = blockIdx.z & 1;
    const int yseg = blockIdx.z >> 1;

    const float* X = dir ? P2 : P1;
    const float* Y = dir ? P1 : P2;
    const float* Xb = X + (size_t)b * NPTS * 3;
    const float* Yb = Y + (size_t)b * NPTS * 3 + (size_t)yseg * CHUNK * 3;

    __shared__ float ys[CHUNK * 3];
    const int tid = threadIdx.x;

    // stage CHUNK y-points (3072 floats = 768 float4, 3 per thread), coalesced
    {
        const float4* src = (const float4*)Yb;
        float4* dst = (float4*)ys;
        #pragma unroll
        for (int t = 0; t < (CHUNK * 3 / 4) / TPB; ++t)
            dst[t * TPB + tid] = src[t * TPB + tid];
    }

    const int rowbase = blockIdx.x * (TPB * XPT);
    float x0[XPT], x1[XPT], x2[XPT], md[XPT];
    #pragma unroll
    for (int k = 0; k < XPT; ++k) {
        int r = rowbase + k * TPB + tid;
        x0[k] = Xb[r * 3 + 0];
        x1[k] = Xb[r * 3 + 1];
        x2[k] = Xb[r * 3 + 2];
        md[k] = 1e30f;
    }
    __syncthreads();

    #pragma unroll 4
    for (int j = 0; j < CHUNK; ++j) {
        // broadcast LDS reads (same address across lanes -> conflict-free)
        float y0 = ys[3 * j + 0];
        float y1 = ys[3 * j + 1];
        float y2 = ys[3 * j + 2];
        #pragma unroll
        for (int k = 0; k < XPT; ++k) {
            float dx = x0[k] - y0;
            float dy = x1[k] - y1;
            float dz = x2[k] - y2;
            float d  = fmaf(dx, dx, fmaf(dy, dy, dz * dz));
            md[k] = fminf(md[k], d);
        }
    }

    // per-row partial min across y-segments: atomicMin on float bits.
    // all d >= 0 (direct squared distance) so uint order == float order.
    unsigned* mrow = minsq + ((size_t)(dir * BATCH + b)) * NPTS;
    #pragma unroll
    for (int k = 0; k < XPT; ++k)
        atomicMin(&mrow[rowbase + k * TPB + tid], __float_as_uint(md[k]));
}

__global__ __launch_bounds__(TPB)
void chamfer_reduce(const unsigned* __restrict__ minsq, float* __restrict__ sum) {
    const int i = blockIdx.x * TPB + threadIdx.x;
    float d = __uint_as_float(minsq[i]);
    float s = sqrtf(d);
    #pragma unroll
    for (int off = 32; off; off >>= 1) s += __shfl_down(s, off, 64);
    __shared__ float ws[TPB / 64];
    const int tid = threadIdx.x;
    if ((tid & 63) == 0) ws[tid >> 6] = s;
    __syncthreads();
    if (tid == 0) {
        float t = 0.f;
        #pragma unroll
        for (int w = 0; w < TPB / 64; ++w) t += ws[w];
        atomicAdd(sum, t);
    }
}

__global__ void chamfer_final(const float* __restrict__ sum, float* __restrict__ out) {
    out[0] = sum[0] * (1.0f / (2.0f * BATCH * NPTS));
}

extern "C" void kernel_launch(void* const* d_in, const int* in_sizes, int n_in,
                              void* d_out, int out_size, void* d_ws, size_t ws_size,
                              hipStream_t stream) {
    const float* p1 = (const float*)d_in[0];
    const float* p2 = (const float*)d_in[1];
    float* out = (float*)d_out;

    const size_t n_rows = 2ull * BATCH * NPTS;      // 65536
    unsigned* minsq = (unsigned*)d_ws;
    float* sum = (float*)((char*)d_ws + n_rows * sizeof(unsigned));

    // init: 0xFFFFFFFF > any non-negative float bit pattern
    hipMemsetAsync(minsq, 0xFF, n_rows * sizeof(unsigned), stream);
    hipMemsetAsync(sum, 0, sizeof(float), stream);

    dim3 gridA(NPTS / (TPB * XPT), BATCH, 2 * YSPLIT);   // (8,4,16) = 512 blocks
    chamfer_partial<<<gridA, TPB, 0, stream>>>(p1, p2, minsq);

    chamfer_reduce<<<dim3(n_rows / TPB), TPB, 0, stream>>>(minsq, sum);

    chamfer_final<<<1, 1, 0, stream>>>(sum, out);
}

// Round 2
// 61.069 us; speedup vs baseline: 1.3362x; 1.3362x over previous
//
#include <hip/hip_runtime.h>
#include <hip/hip_bf16.h>

// Chamfer distance, B=4, N=M=8192, fp32.
// d(x,y) = |x|^2 - 2 x.y + |y|^2  (the reference's own expansion).
// Per row we min over d' = |y|^2 - 2 x.y (constant |x|^2 shift preserves argmin),
// add |x|^2 back at the end, clamp >= 0, sqrt, mean.
// Inner loop uses packed fp32: v_pk_fma_f32 (2 pairs per instr) + v_min3_f32.

typedef float f32x2 __attribute__((ext_vector_type(2)));
typedef float f32x4 __attribute__((ext_vector_type(4)));

constexpr int TPB    = 256;
constexpr int XPT    = 8;     // rows per thread -> 2048 rows/block
constexpr int CHUNK  = 256;   // y-points per block
constexpr int YSPLIT = 32;    // 8192 / 256
constexpr int NPTS   = 8192;
constexpr int BATCH  = 4;
constexpr int NROWS  = 2 * BATCH * NPTS;   // 65536

__device__ __forceinline__ f32x2 pk_fma(f32x2 a, f32x2 b, f32x2 c) {
    f32x2 d;
    asm("v_pk_fma_f32 %0, %1, %2, %3" : "=v"(d) : "v"(a), "v"(b), "v"(c));
    return d;
}

template<bool USE_TABLE>
__global__ __launch_bounds__(TPB, 4)
void chamfer_partial(const float* __restrict__ P1, const float* __restrict__ P2,
                     float* __restrict__ table, unsigned* __restrict__ amin) {
    const int b    = blockIdx.y;
    const int dir  = blockIdx.z & 1;
    const int yseg = blockIdx.z >> 1;

    const float* X = (dir ? P2 : P1) + (size_t)b * NPTS * 3;
    const float* Y = (dir ? P1 : P2) + (size_t)b * NPTS * 3 + (size_t)yseg * CHUNK * 3;

    __shared__ f32x4 ys0[CHUNK / 4], ys1[CHUNK / 4], ys2[CHUNK / 4], ys3[CHUNK / 4];
    const int tid = threadIdx.x;

    // stage CHUNK y-points, AoS -> SoA, plus |y|^2  (CHUNK == TPB: one point/thread)
    {
        float a = Y[3 * tid + 0], bb = Y[3 * tid + 1], c = Y[3 * tid + 2];
        ((float*)ys0)[tid] = a;
        ((float*)ys1)[tid] = bb;
        ((float*)ys2)[tid] = c;
        ((float*)ys3)[tid] = fmaf(a, a, fmaf(bb, bb, c * c));
    }

    const int rowbase = blockIdx.x * (TPB * XPT);
    f32x2 nx0[XPT], nx1[XPT], nx2[XPT];
    float x2s[XPT], md[XPT];
    #pragma unroll
    for (int k = 0; k < XPT; ++k) {
        int r = rowbase + k * TPB + tid;
        float a = X[3 * r + 0], bb = X[3 * r + 1], c = X[3 * r + 2];
        float na = -2.f * a, nb = -2.f * bb, nc = -2.f * c;
        nx0[k] = {na, na};
        nx1[k] = {nb, nb};
        nx2[k] = {nc, nc};
        x2s[k] = fmaf(a, a, fmaf(bb, bb, c * c));
        md[k]  = 1e30f;
    }
    __syncthreads();

    #pragma unroll 2
    for (int j = 0; j < CHUNK / 4; ++j) {
        // uniform-address ds_read_b128: broadcast, conflict-free
        f32x4 q0 = ys0[j], q1 = ys1[j], q2 = ys2[j], qs = ys3[j];
        f32x2 y0l = q0.lo, y0h = q0.hi;
        f32x2 y1l = q1.lo, y1h = q1.hi;
        f32x2 y2l = q2.lo, y2h = q2.hi;
        f32x2 ysl = qs.lo, ysh = qs.hi;
        #pragma unroll
        for (int k = 0; k < XPT; ++k) {
            f32x2 a = pk_fma(nx0[k], y0l, ysl);   // d' = |y|^2 - 2 x.y
            a = pk_fma(nx1[k], y1l, a);
            a = pk_fma(nx2[k], y2l, a);
            f32x2 c2 = pk_fma(nx0[k], y0h, ysh);
            c2 = pk_fma(nx1[k], y1h, c2);
            c2 = pk_fma(nx2[k], y2h, c2);
            float t = fminf(fminf(md[k], a.x), a.y);    // v_min3_f32
            md[k]   = fminf(fminf(t, c2.x), c2.y);      // v_min3_f32
        }
    }

    const size_t rowoff = (size_t)(dir * BATCH + b) * NPTS + rowbase;
    #pragma unroll
    for (int k = 0; k < XPT; ++k) {
        float d = fmaxf(md[k] + x2s[k], 0.f);
        if (USE_TABLE)
            table[(size_t)yseg * NROWS + rowoff + k * TPB + tid] = d;
        else
            atomicMin(&amin[rowoff + k * TPB + tid], __float_as_uint(d));
    }
}

template<bool USE_TABLE>
__global__ __launch_bounds__(TPB)
void chamfer_reduce(const float* __restrict__ table, const unsigned* __restrict__ amin,
                    float* __restrict__ sum) {
    const int r = blockIdx.x * TPB + threadIdx.x;
    float m;
    if (USE_TABLE) {
        m = 1e30f;
        #pragma unroll 8
        for (int s = 0; s < YSPLIT; ++s)
            m = fminf(m, table[(size_t)s * NROWS + r]);   // coalesced across threads
    } else {
        m = __uint_as_float(amin[r]);
    }
    float v = sqrtf(fmaxf(m, 0.f));
    #pragma unroll
    for (int off = 32; off; off >>= 1) v += __shfl_down(v, off, 64);
    __shared__ float ws[TPB / 64];
    const int tid = threadIdx.x;
    if ((tid & 63) == 0) ws[tid >> 6] = v;
    __syncthreads();
    if (tid == 0) {
        float t = 0.f;
        #pragma unroll
        for (int w = 0; w < TPB / 64; ++w) t += ws[w];
        atomicAdd(sum, t);
    }
}

__global__ void chamfer_final(const float* __restrict__ sum, float* __restrict__ out) {
    out[0] = sum[0] * (1.0f / NROWS);   // (d1+d2)/2 with equal counts
}

extern "C" void kernel_launch(void* const* d_in, const int* in_sizes, int n_in,
                              void* d_out, int out_size, void* d_ws, size_t ws_size,
                              hipStream_t stream) {
    const float* p1 = (const float*)d_in[0];
    const float* p2 = (const float*)d_in[1];
    float* out = (float*)d_out;

    const size_t table_bytes = (size_t)NROWS * YSPLIT * sizeof(float);   // 8 MB
    const bool use_table = ws_size >= table_bytes + sizeof(float);

    dim3 gridA(NPTS / (TPB * XPT), BATCH, 2 * YSPLIT);   // (4,4,64) = 1024 blocks

    if (use_table) {
        float* table = (float*)d_ws;
        float* sum   = (float*)((char*)d_ws + table_bytes);
        hipMemsetAsync(sum, 0, sizeof(float), stream);
        chamfer_partial<true><<<gridA, TPB, 0, stream>>>(p1, p2, table, nullptr);
        chamfer_reduce<true><<<dim3(NROWS / TPB), TPB, 0, stream>>>(table, nullptr, sum);
        chamfer_final<<<1, 1, 0, stream>>>(sum, out);
    } else {
        unsigned* amin = (unsigned*)d_ws;
        float* sum = (float*)((char*)d_ws + (size_t)NROWS * sizeof(unsigned));
        hipMemsetAsync(amin, 0xFF, (size_t)NROWS * sizeof(unsigned), stream);
        hipMemsetAsync(sum, 0, sizeof(float), stream);
        chamfer_partial<false><<<gridA, TPB, 0, stream>>>(p1, p2, nullptr, amin);
        chamfer_reduce<false><<<dim3(NROWS / TPB), TPB, 0, stream>>>(nullptr, amin, sum);
        chamfer_final<<<1, 1, 0, stream>>>(sum, out);
    }
}